// Round 5
// baseline (149.022 us; speedup 1.0000x reference)
//
#include <hip/hip_runtime.h>
#include <math.h>

#define KNN 8
#define QPB 16          // queries per block
#define SUB 16          // sub-lanes per query
#define BLK 256         // QPB*SUB threads, 4 waves
#define CAP 1024        // staged candidates per LDS tile
#define NBT 258         // batch-id table capacity

// One fused kernel:
//   wave-cooperative range search -> stage coords in LDS (single-batch fast
//   path skips b1 tables) -> 16-way sliced top-8 scan -> exact lexicographic
//   (d, idx) shuffle merge -> LDS-broadcast gather + MSE partial ->
//   last-block-done deterministic final reduction.
__launch_bounds__(BLK, 4)
__global__ void knn_fused(const float* __restrict__ x1,
                          const float* __restrict__ x2,
                          const int* __restrict__ b1,
                          const int* __restrict__ b2,
                          int N, int ROW, float scale,
                          float* __restrict__ ws_part,
                          unsigned* __restrict__ counter,
                          float* __restrict__ out) {
  __shared__ float4 c4[CAP];          // {x, y, z, |c|^2}
  __shared__ int   bs[CAP];           // staged b1 (mixed-batch path only)
  __shared__ int   sstart[NBT];       // first in-tile row of batch b
  __shared__ int   send[NBT];         // last+1 in-tile row of batch b
  __shared__ int   s_info[4];         // {s1, e1, b_first, b_last}
  __shared__ float2 nbrs[QPB][KNN];   // merged (d, idx) per query
  __shared__ float wred[BLK / 64];
  __shared__ int   s_last;

  const int tid  = threadIdx.x;
  const int lane = tid & 63;
  const int wv   = tid >> 6;
  const int qi   = tid >> 4;          // query within block (SUB=16)
  const int sub  = tid & (SUB - 1);
  const int q0   = blockIdx.x * QPB;
  const int q    = q0 + qi;
  const int qlast = min(q0 + QPB - 1, N - 1);

  // Wave-cooperative lower_bound on b1 (64-way fanout, ~3 dependent rounds).
  if (wv < 2) {
    const int bb = (wv == 0) ? b2[q0] : b2[qlast];
    const int target = bb + wv;       // wv0: lb(b_first), wv1: lb(b_last+1)
    int lo = 0, hi = N;
    while (lo < hi) {
      int step = (hi - lo + 63) >> 6;
      int p = lo + lane * step;
      bool pred = (p < hi) && (b1[p] < target);
      int c = __popcll(__ballot(pred));
      if (c == 0) { hi = lo; break; }
      int nlo = lo + (c - 1) * step + 1;
      hi = min(hi, lo + c * step);
      lo = nlo;
    }
    if (lane == 0) { s_info[wv] = lo; s_info[2 + wv] = bb; }
  }

  float qx = 0.f, qy = 0.f, qz = 0.f; int mybatch = -1;
  if (q < N) {
    const float* c2 = x2 + (size_t)q * ROW;
    qx = c2[0]; qy = c2[1]; qz = c2[2];
    mybatch = b2[q];
  }
  const float n2 = qx * qx + qy * qy + qz * qz;

  float dist[KNN]; int nidx[KNN];
#pragma unroll
  for (int k = 0; k < KNN; ++k) { dist[k] = INFINITY; nidx[k] = 0; }

  __syncthreads();
  const int s1 = s_info[0], e1 = s_info[1];
  const bool single = (s_info[2] == s_info[3]);   // block-uniform

  for (int t0 = s1; t0 < e1; t0 += CAP) {
    const int t1 = min(t0 + CAP, e1);
    const int L  = t1 - t0;
    if (!single) {
      for (int i = tid; i < NBT; i += BLK) { sstart[i] = CAP; send[i] = 0; }
    }
    __syncthreads();                   // guards c4/bs reuse + table init
    for (int i = t0 + tid; i < t1; i += BLK) {
      const float* p = x1 + (size_t)i * ROW;
      float cx = p[0], cy = p[1], cz = p[2];
      int li = i - t0;
      c4[li] = make_float4(cx, cy, cz, cx * cx + cy * cy + cz * cz);
      if (!single) bs[li] = b1[i];
    }
    __syncthreads();
    int lo, hi;
    if (single) {
      lo = 0; hi = (q < N) ? L : 0;
    } else {
      // boundary tables from LDS (unique writer per entry)
      for (int li = tid; li < L; li += BLK) {
        int bc = bs[li];
        int bp = (li == 0)     ? (bc ^ 1) : bs[li - 1];
        int bn = (li == L - 1) ? (bc ^ 1) : bs[li + 1];
        if (bc != bp) sstart[bc] = li;
        if (bc != bn) send[bc]  = li + 1;
      }
      __syncthreads();
      lo = CAP; hi = 0;
      if (mybatch >= 0) { lo = sstart[mybatch]; hi = send[mybatch]; }
    }
    int j = lo + sub;
    if (j < hi) {
      float4 c = c4[j];
      while (true) {
        int jn = j + SUB;
        bool more = jn < hi;
        float4 cn = c4[more ? jn : j];
        float d = fmaf(-2.0f, fmaf(qx, c.x, fmaf(qy, c.y, qz * c.z)), n2 + c.w);
        d = fmaxf(d, 0.0f);
        // strict < : ascending j => ties keep earlier index within a slice
        if (d < dist[KNN - 1]) {
          dist[KNN - 1] = d; nidx[KNN - 1] = t0 + j;
#pragma unroll
          for (int k = KNN - 1; k > 0; --k) {
            if (dist[k] < dist[k - 1]) {
              float td = dist[k]; dist[k] = dist[k - 1]; dist[k - 1] = td;
              int ti = nidx[k]; nidx[k] = nidx[k - 1]; nidx[k - 1] = ti;
            }
          }
        }
        if (!more) break;
        j = jn; c = cn;
      }
    }
  }

  // Exact 16-way merge of sorted per-slice lists: each round extracts the
  // lexicographic (d, idx) min across the 16-lane group.
  float md[KNN]; int mi[KNN];
#pragma unroll
  for (int r = 0; r < KNN; ++r) {
    float hd = dist[0]; int hidx = nidx[0];
    float bd = hd; int bi = hidx;
#pragma unroll
    for (int m = 1; m <= 8; m <<= 1) {
      float od = __shfl_xor(bd, m); int oi = __shfl_xor(bi, m);
      if (od < bd || (od == bd && oi < bi)) { bd = od; bi = oi; }
    }
    md[r] = bd; mi[r] = bi;
    if (hd == bd && hidx == bi) {   // unique for real entries; (inf,0) pads multi-pop harmlessly
#pragma unroll
      for (int k = 0; k < KNN - 1; ++k) { dist[k] = dist[k + 1]; nidx[k] = nidx[k + 1]; }
      dist[KNN - 1] = INFINITY; nidx[KNN - 1] = 0;
    }
  }

  if (sub == 0 && q < N) {
#pragma unroll
    for (int r = 0; r < KNN; ++r)
      nbrs[qi][r] = make_float2(md[r], __int_as_float(mi[r]));
  }
  __syncthreads();

  // Gather + MSE: wave wv owns queries q0+4*wv..+3; neighbor lists via
  // broadcast ds_read_b128 (conflict-free); lane l owns dims l and l+64.
  float pacc = 0.0f;
#pragma unroll
  for (int qq = 0; qq < QPB / 4; ++qq) {
    const int lq = wv * (QPB / 4) + qq;
    const int gq = q0 + lq;
    if (gq < N) {                      // wave-uniform
      const float4* pn = (const float4*)&nbrs[lq][0];
      float4 n01 = pn[0], n23 = pn[1], n45 = pn[2], n67 = pn[3];
      float dd[KNN] = {n01.x, n01.z, n23.x, n23.z, n45.x, n45.z, n67.x, n67.z};
      int   id[KNN] = {__float_as_int(n01.y), __float_as_int(n01.w),
                       __float_as_int(n23.y), __float_as_int(n23.w),
                       __float_as_int(n45.y), __float_as_int(n45.w),
                       __float_as_int(n67.y), __float_as_int(n67.w)};
      float w[KNN]; float sw = 0.0f;
#pragma unroll
      for (int r = 0; r < KNN; ++r) { w[r] = 1.0f / fmaxf(dd[r], 1e-16f); sw += w[r]; }
      float acc0 = 0.0f, acc1 = 0.0f;
#pragma unroll
      for (int r = 0; r < KNN; ++r) {
        const float* f = x1 + (size_t)id[r] * ROW + 3;
        acc0 += w[r] * f[lane];
        acc1 += w[r] * f[lane + 64];
      }
      const float* f2 = x2 + (size_t)gq * ROW + 3;
      float rinv = 1.0f / sw;
      float e0 = acc0 * rinv - f2[lane];
      float e1 = acc1 * rinv - f2[lane + 64];
      pacc += e0 * e0 + e1 * e1;
    }
  }
#pragma unroll
  for (int off = 32; off > 0; off >>= 1) pacc += __shfl_xor(pacc, off);
  if (lane == 0) wred[wv] = pacc;
  __syncthreads();
  if (tid == 0) {
    ws_part[blockIdx.x] = (wred[0] + wred[1]) + (wred[2] + wred[3]);
  }

  // Last-block-done final reduction (deterministic: fixed index order,
  // independent of which block runs it).
  __threadfence();                       // release ws_part write (device scope)
  if (tid == 0) {
    unsigned old = atomicAdd(counter, 1u);
    s_last = (old == gridDim.x - 1) ? 1 : 0;
  }
  __syncthreads();
  if (s_last) {
    __threadfence();                     // acquire others' ws_part writes
    float s = 0.0f;
    for (int i = tid; i < (int)gridDim.x; i += BLK) s += ws_part[i];
    float* sm = (float*)c4;              // reuse LDS
    sm[tid] = s;
    __syncthreads();
    for (int st = 128; st > 0; st >>= 1) {
      if (tid < st) sm[tid] += sm[tid + st];
      __syncthreads();
    }
    if (tid == 0) out[0] = sm[0] * scale;
  }
}

extern "C" void kernel_launch(void* const* d_in, const int* in_sizes, int n_in,
                              void* d_out, int out_size, void* d_ws, size_t ws_size,
                              hipStream_t stream) {
  const float* x1 = (const float*)d_in[0];
  const float* x2 = (const float*)d_in[1];
  const int* b1 = (const int*)d_in[2];
  const int* b2 = (const int*)d_in[3];
  int N = in_sizes[2];            // 16384
  int ROW = in_sizes[0] / N;      // 131
  float* out = (float*)d_out;

  int blocks = (N + QPB - 1) / QPB;              // 1024
  float* ws_part = (float*)d_ws;
  unsigned* counter = (unsigned*)((char*)d_ws + (size_t)blocks * sizeof(float));
  if (ws_size < (size_t)blocks * sizeof(float) + sizeof(unsigned)) return;

  hipMemsetAsync(counter, 0, sizeof(unsigned), stream);
  float scale = 1.0f / ((float)N * (float)(ROW - 3));
  knn_fused<<<blocks, BLK, 0, stream>>>(x1, x2, b1, b2, N, ROW, scale,
                                        ws_part, counter, out);
}

// Round 6
// 29.301 us; speedup vs baseline: 5.0860x; 5.0860x over previous
//
#include <hip/hip_runtime.h>
#include <math.h>

#define KNN 8
#define QPB 16          // queries per block
#define SUB 32          // sub-lanes per query
#define BLK 512         // QPB*SUB threads, 8 waves
#define CAP 1024        // staged candidates per LDS tile
#define NBT 258         // batch-id table capacity

// Fused select+gather: wave-cooperative range search -> stage coords in LDS
// (single-batch fast path skips b1 tables) -> 32-way sliced top-8 scan ->
// exact lexicographic (d, idx) shuffle merge -> LDS-broadcast gather + MSE
// partial. One deterministic partial per block. NO device-scope fences.
__launch_bounds__(BLK, 8)
__global__ void knn_fused(const float* __restrict__ x1,
                          const float* __restrict__ x2,
                          const int* __restrict__ b1,
                          const int* __restrict__ b2,
                          int N, int ROW,
                          float* __restrict__ ws_part) {
  __shared__ float4 c4[CAP];          // {x, y, z, |c|^2}
  __shared__ int   bs[CAP];           // staged b1 (mixed-batch path only)
  __shared__ int   sstart[NBT];       // first in-tile row of batch b
  __shared__ int   send[NBT];         // last+1 in-tile row of batch b
  __shared__ int   s_info[4];         // {s1, e1, b_first, b_last}
  __shared__ float2 nbrs[QPB][KNN];   // merged (d, idx) per query
  __shared__ float wred[BLK / 64];

  const int tid  = threadIdx.x;
  const int lane = tid & 63;
  const int wv   = tid >> 6;          // 0..7
  const int qi   = tid >> 5;          // query within block (SUB=32)
  const int sub  = tid & (SUB - 1);
  const int q0   = blockIdx.x * QPB;
  const int q    = q0 + qi;
  const int qlast = min(q0 + QPB - 1, N - 1);

  // Wave-cooperative lower_bound on b1 (64-way fanout, ~3 dependent rounds).
  if (wv < 2) {
    const int bb = (wv == 0) ? b2[q0] : b2[qlast];
    const int target = bb + wv;       // wv0: lb(b_first), wv1: lb(b_last+1)
    int lo = 0, hi = N;
    while (lo < hi) {
      int step = (hi - lo + 63) >> 6;
      int p = lo + lane * step;
      bool pred = (p < hi) && (b1[p] < target);
      int c = __popcll(__ballot(pred));
      if (c == 0) { hi = lo; break; }
      int nlo = lo + (c - 1) * step + 1;
      hi = min(hi, lo + c * step);
      lo = nlo;
    }
    if (lane == 0) { s_info[wv] = lo; s_info[2 + wv] = bb; }
  }

  float qx = 0.f, qy = 0.f, qz = 0.f; int mybatch = -1;
  if (q < N) {
    const float* c2 = x2 + (size_t)q * ROW;
    qx = c2[0]; qy = c2[1]; qz = c2[2];
    mybatch = b2[q];
  }
  const float n2 = qx * qx + qy * qy + qz * qz;

  float dist[KNN]; int nidx[KNN];
#pragma unroll
  for (int k = 0; k < KNN; ++k) { dist[k] = INFINITY; nidx[k] = 0; }

  __syncthreads();
  const int s1 = s_info[0], e1 = s_info[1];
  const bool single = (s_info[2] == s_info[3]);   // block-uniform

  for (int t0 = s1; t0 < e1; t0 += CAP) {
    const int t1 = min(t0 + CAP, e1);
    const int L  = t1 - t0;
    if (!single) {
      for (int i = tid; i < NBT; i += BLK) { sstart[i] = CAP; send[i] = 0; }
    }
    __syncthreads();                   // guards c4/bs reuse + table init
    for (int i = t0 + tid; i < t1; i += BLK) {
      const float* p = x1 + (size_t)i * ROW;
      float cx = p[0], cy = p[1], cz = p[2];
      int li = i - t0;
      c4[li] = make_float4(cx, cy, cz, cx * cx + cy * cy + cz * cz);
      if (!single) bs[li] = b1[i];
    }
    __syncthreads();
    int lo, hi;
    if (single) {
      lo = 0; hi = (q < N) ? L : 0;
    } else {
      // boundary tables from LDS (unique writer per entry)
      for (int li = tid; li < L; li += BLK) {
        int bc = bs[li];
        int bp = (li == 0)     ? (bc ^ 1) : bs[li - 1];
        int bn = (li == L - 1) ? (bc ^ 1) : bs[li + 1];
        if (bc != bp) sstart[bc] = li;
        if (bc != bn) send[bc]  = li + 1;
      }
      __syncthreads();
      lo = CAP; hi = 0;
      if (mybatch >= 0) { lo = sstart[mybatch]; hi = send[mybatch]; }
    }
    int j = lo + sub;
    if (j < hi) {
      float4 c = c4[j];
      while (true) {
        int jn = j + SUB;
        bool more = jn < hi;
        float4 cn = c4[more ? jn : j];
        float d = fmaf(-2.0f, fmaf(qx, c.x, fmaf(qy, c.y, qz * c.z)), n2 + c.w);
        d = fmaxf(d, 0.0f);
        // strict < : ascending j => ties keep earlier index within a slice
        if (d < dist[KNN - 1]) {
          dist[KNN - 1] = d; nidx[KNN - 1] = t0 + j;
#pragma unroll
          for (int k = KNN - 1; k > 0; --k) {
            if (dist[k] < dist[k - 1]) {
              float td = dist[k]; dist[k] = dist[k - 1]; dist[k - 1] = td;
              int ti = nidx[k]; nidx[k] = nidx[k - 1]; nidx[k - 1] = ti;
            }
          }
        }
        if (!more) break;
        j = jn; c = cn;
      }
    }
  }

  // Exact 32-way merge of sorted per-slice lists: each round extracts the
  // lexicographic (d, idx) min across the 32-lane group.
  float md[KNN]; int mi[KNN];
#pragma unroll
  for (int r = 0; r < KNN; ++r) {
    float hd = dist[0]; int hidx = nidx[0];
    float bd = hd; int bi = hidx;
#pragma unroll
    for (int m = 1; m <= 16; m <<= 1) {
      float od = __shfl_xor(bd, m); int oi = __shfl_xor(bi, m);
      if (od < bd || (od == bd && oi < bi)) { bd = od; bi = oi; }
    }
    md[r] = bd; mi[r] = bi;
    if (hd == bd && hidx == bi) {   // unique for real entries; (inf,0) pads multi-pop harmlessly
#pragma unroll
      for (int k = 0; k < KNN - 1; ++k) { dist[k] = dist[k + 1]; nidx[k] = nidx[k + 1]; }
      dist[KNN - 1] = INFINITY; nidx[KNN - 1] = 0;
    }
  }

  if (sub == 0 && q < N) {
#pragma unroll
    for (int r = 0; r < KNN; ++r)
      nbrs[qi][r] = make_float2(md[r], __int_as_float(mi[r]));
  }
  __syncthreads();

  // Gather + MSE: wave wv owns queries q0+2*wv..+1; neighbor lists via
  // broadcast ds_read_b128 (conflict-free); lane l owns dims l and l+64.
  float pacc = 0.0f;
#pragma unroll
  for (int qq = 0; qq < QPB / (BLK / 64); ++qq) {
    const int lq = wv * (QPB / (BLK / 64)) + qq;
    const int gq = q0 + lq;
    if (gq < N) {                      // wave-uniform
      const float4* pn = (const float4*)&nbrs[lq][0];
      float4 n01 = pn[0], n23 = pn[1], n45 = pn[2], n67 = pn[3];
      float dd[KNN] = {n01.x, n01.z, n23.x, n23.z, n45.x, n45.z, n67.x, n67.z};
      int   id[KNN] = {__float_as_int(n01.y), __float_as_int(n01.w),
                       __float_as_int(n23.y), __float_as_int(n23.w),
                       __float_as_int(n45.y), __float_as_int(n45.w),
                       __float_as_int(n67.y), __float_as_int(n67.w)};
      float w[KNN]; float sw = 0.0f;
#pragma unroll
      for (int r = 0; r < KNN; ++r) { w[r] = 1.0f / fmaxf(dd[r], 1e-16f); sw += w[r]; }
      float acc0 = 0.0f, acc1 = 0.0f;
#pragma unroll
      for (int r = 0; r < KNN; ++r) {
        const float* f = x1 + (size_t)id[r] * ROW + 3;
        acc0 += w[r] * f[lane];
        acc1 += w[r] * f[lane + 64];
      }
      const float* f2 = x2 + (size_t)gq * ROW + 3;
      float rinv = 1.0f / sw;
      float e0 = acc0 * rinv - f2[lane];
      float e1 = acc1 * rinv - f2[lane + 64];
      pacc += e0 * e0 + e1 * e1;
    }
  }
#pragma unroll
  for (int off = 32; off > 0; off >>= 1) pacc += __shfl_xor(pacc, off);
  if (lane == 0) wred[wv] = pacc;
  __syncthreads();
  if (tid == 0) {
    float s = 0.0f;
#pragma unroll
    for (int w = 0; w < BLK / 64; ++w) s += wred[w];
    ws_part[blockIdx.x] = s;
  }
}

// Deterministic final reduction + mean scale.
__global__ void knn_final(const float* __restrict__ part, int n,
                          float scale, float* __restrict__ out) {
  __shared__ float sm[256];
  float s = 0.0f;
  for (int i = threadIdx.x; i < n; i += 256) s += part[i];
  sm[threadIdx.x] = s;
  __syncthreads();
  for (int step = 128; step > 0; step >>= 1) {
    if (threadIdx.x < step) sm[threadIdx.x] += sm[threadIdx.x + step];
    __syncthreads();
  }
  if (threadIdx.x == 0) out[0] = sm[0] * scale;
}

extern "C" void kernel_launch(void* const* d_in, const int* in_sizes, int n_in,
                              void* d_out, int out_size, void* d_ws, size_t ws_size,
                              hipStream_t stream) {
  const float* x1 = (const float*)d_in[0];
  const float* x2 = (const float*)d_in[1];
  const int* b1 = (const int*)d_in[2];
  const int* b2 = (const int*)d_in[3];
  int N = in_sizes[2];            // 16384
  int ROW = in_sizes[0] / N;      // 131
  float* out = (float*)d_out;

  int blocks = (N + QPB - 1) / QPB;              // 1024
  float* ws_part = (float*)d_ws;
  if (ws_size < (size_t)blocks * sizeof(float)) return;

  knn_fused<<<blocks, BLK, 0, stream>>>(x1, x2, b1, b2, N, ROW, ws_part);
  float scale = 1.0f / ((float)N * (float)(ROW - 3));
  knn_final<<<1, 256, 0, stream>>>(ws_part, blocks, scale, out);
}